// Round 4
// baseline (317.175 us; speedup 1.0000x reference)
//
#include <hip/hip_runtime.h>
#include <hip/hip_bf16.h>

typedef __attribute__((ext_vector_type(8))) short short8;
typedef __attribute__((ext_vector_type(4))) float f32x4;
typedef __attribute__((ext_vector_type(2))) float f32x2;
typedef __attribute__((ext_vector_type(16))) float f32x16;
typedef __attribute__((ext_vector_type(4))) unsigned short u16x4;
typedef __attribute__((ext_vector_type(8))) unsigned short u16x8;

#define M_TOT 16384
#define N_TOT 2048
#define K_TOT 2048

__device__ __forceinline__ unsigned short f2bf(float f) {
  unsigned u = __builtin_bit_cast(unsigned, f);
  u += 0x7FFFu + ((u >> 16) & 1u);   // RNE
  return (unsigned short)(u >> 16);
}
__device__ __forceinline__ float bf2f(unsigned short h) {
  return __builtin_bit_cast(float, (unsigned)h << 16);
}

// ===================== TILED FAST PATH ======================================
// ws: Whi_f[4M ush] Wlo_f[4M ush] Xhi_t[32M ush] T[32768 f32] CU[4096 f32]
// W: FRAGMENT-ORDER for 32x32x16 MFMA B-operand:
//    flat = (nblk32*128 + kblk16)*512 + (col + 32*khalf)*8 + e
//    so lane l's dwordx4 at (nb*128+kb)*512 + l*8 is exactly its B fragment.
// A: [M/256][K/32] tiles of [256 rows][32 k] bf16 = 16KB, XOR-swizzled
//    (byte inner = (row*64 + chunk16*16) ^ ((row&7)<<4), staged linearly).

__global__ void wsplit_frag(const float* __restrict__ Wb, const float* __restrict__ U,
                            const float* __restrict__ S, const float* __restrict__ Vh,
                            const float* __restrict__ P, const float* __restrict__ gv,
                            unsigned short* __restrict__ Whi_f,
                            unsigned short* __restrict__ Wlo_f,
                            float* __restrict__ CU) {
  float c0 = 0.f, c1 = 0.f;
#pragma unroll
  for (int u = 0; u < 16; ++u) { c0 += gv[u] * P[2 * u]; c1 += gv[u] * P[2 * u + 1]; }
  c0 *= S[0]; c1 *= S[1];
  int t = blockIdx.x * 256 + threadIdx.x;
  int o = t >> 8;            // W row (n) 0..2047
  int c = t & 255;           // 8-elem k-chunk
  int k = c << 3;
  f32x4 wb0 = *(const f32x4*)(Wb + (size_t)o * K_TOT + k);
  f32x4 wb1 = *(const f32x4*)(Wb + (size_t)o * K_TOT + k + 4);
  f32x4 v0a = *(const f32x4*)(Vh + k);
  f32x4 v0b = *(const f32x4*)(Vh + k + 4);
  f32x4 v1a = *(const f32x4*)(Vh + K_TOT + k);
  f32x4 v1b = *(const f32x4*)(Vh + K_TOT + k + 4);
  float u0 = U[2 * o] * c0, u1 = U[2 * o + 1] * c1;
  u16x8 hi, lo;
#pragma unroll
  for (int q = 0; q < 4; ++q) {
    float w = wb0[q] + u0 * v0a[q] + u1 * v1a[q];
    unsigned short h = f2bf(w);
    hi[q] = h; lo[q] = f2bf(w - bf2f(h));
  }
#pragma unroll
  for (int q = 0; q < 4; ++q) {
    float w = wb1[q] + u0 * v0b[q] + u1 * v1b[q];
    unsigned short h = f2bf(w);
    hi[4 + q] = h; lo[4 + q] = f2bf(w - bf2f(h));
  }
  int kb = c >> 1, kh = c & 1;
  int nb = o >> 5, col = o & 31;
  size_t base = ((size_t)nb * 128 + kb) * 512 + ((col + (kh << 5)) << 3);
  *(u16x8*)(Whi_f + base) = hi;
  *(u16x8*)(Wlo_f + base) = lo;
  if (c == 0) {
    CU[2 * o]     = c0 * U[2 * o];
    CU[2 * o + 1] = c1 * U[2 * o + 1];
  }
}

// x -> bf16 hi (R2-format tiles); T[m][r] = sum_k (x - x_hi)[m,k] * Vh[r,k]
__global__ void xsplit_tiled(const float* __restrict__ X, const float* __restrict__ Vh,
                             unsigned short* __restrict__ Xhi_t, float* __restrict__ T) {
  int w = threadIdx.x >> 6, lane = threadIdx.x & 63;
  int m = blockIdx.x * 4 + w;
  const float* xr = X + (size_t)m * K_TOT;
  float t0 = 0.f, t1 = 0.f;
#pragma unroll
  for (int p = 0; p < 4; ++p) {
    int c = lane + (p << 6);   // chunk 0..255
    int k = c << 3;
    f32x4 x0 = *(const f32x4*)(xr + k);
    f32x4 x1 = *(const f32x4*)(xr + k + 4);
    f32x4 v0a = *(const f32x4*)(Vh + k);
    f32x4 v0b = *(const f32x4*)(Vh + k + 4);
    f32x4 v1a = *(const f32x4*)(Vh + K_TOT + k);
    f32x4 v1b = *(const f32x4*)(Vh + K_TOT + k + 4);
    u16x8 hi;
#pragma unroll
    for (int q = 0; q < 4; ++q) {
      unsigned short h = f2bf(x0[q]); hi[q] = h;
      float r = x0[q] - bf2f(h);
      t0 += r * v0a[q]; t1 += r * v1a[q];
    }
#pragma unroll
    for (int q = 0; q < 4; ++q) {
      unsigned short h = f2bf(x1[q]); hi[4 + q] = h;
      float r = x1[q] - bf2f(h);
      t0 += r * v0b[q]; t1 += r * v1b[q];
    }
    int kt = c >> 2;
    size_t base = (size_t)((m >> 8) * 64 + kt) * 16384;            // bytes
    int inner = (((m & 255) << 6) + ((c & 3) << 4)) ^ ((m & 7) << 4);
    *(u16x8*)((char*)Xhi_t + base + inner) = hi;
  }
#pragma unroll
  for (int d = 32; d; d >>= 1) {
    t0 += __shfl_xor(t0, d, 64);
    t1 += __shfl_xor(t1, d, 64);
  }
  if (lane == 0) { T[2 * m] = t0; T[2 * m + 1] = t1; }
}

// 2-product GEMM, 32x32x16 MFMA. BM=256 BN=128 BK=32, 4 waves (2Mx2N),
// wave tile 128x64. A via LDS (16KB, single buffer, R2 schedule);
// B direct global->reg fragment loads (L2-resident, zero LDS traffic).
__global__ __launch_bounds__(256, 2) void gemm4_kernel(
    const unsigned short* __restrict__ Xhi_t, const unsigned short* __restrict__ Whi_f,
    const unsigned short* __restrict__ Wlo_f, const float* __restrict__ bias,
    const float* __restrict__ T, const float* __restrict__ CU,
    float* __restrict__ out) {
  __shared__ unsigned short sA[8192];   // 16 KB swizzled A image

  const int tid = threadIdx.x, lane = tid & 63, w = tid >> 6;
  const int wr = w >> 1, wc = w & 1;        // 2M x 2N wave grid
  const int l31 = lane & 31, g = (lane >> 5) & 1;

  // bijective XCD swizzle: 1024 blocks, 1024%8==0
  const int bid = blockIdx.x;
  const int nbk = ((bid & 7) << 7) | (bid >> 3);
  const int bn = nbk & 15, bm = nbk >> 4;

  f32x16 acc[4][2] = {};

  const unsigned short* At = Xhi_t + (size_t)bm * (64 * 8192);

  // A-frag swizzled byte offsets (g in bit4; ks toggles bit5 via XOR)
  int aoff[4];
#pragma unroll
  for (int i = 0; i < 4; ++i) {
    int row = (wr << 7) + (i << 5) + l31;
    aoff[i] = ((row << 6) + (g << 4)) ^ ((l31 & 7) << 4);
  }
  // B fragment base indices (elements): (nb*128 + kb)*512 + lane*8
  int nb0 = (bn << 2) + (wc << 1);

  for (int kt = 0; kt < 64; ++kt) {
    // B fragments for this kt -> registers (global, L2-hot; issued early)
    short8 bh[2][2], bl[2][2];
#pragma unroll
    for (int j = 0; j < 2; ++j)
#pragma unroll
      for (int ks = 0; ks < 2; ++ks) {
        int off = (((nb0 + j) << 7) + (kt << 1) + ks) << 9;
        bh[j][ks] = *(const short8*)(Whi_f + off + (lane << 3));
        bl[j][ks] = *(const short8*)(Wlo_f + off + (lane << 3));
      }

    __syncthreads();  // all waves done reading sA (tile kt-1)

    // stage A tile kt: 16 chunks x 1KB, wave w -> chunks 4w..4w+3
#pragma unroll
    for (int ii = 0; ii < 4; ++ii) {
      int ch = (w << 2) + ii;
      __builtin_amdgcn_global_load_lds(
          (const __attribute__((address_space(1))) void*)(At + (size_t)kt * 8192 + ch * 512 + lane * 8),
          (__attribute__((address_space(3))) void*)(&sA[ch * 512]), 16, 0, 0);
    }
    __syncthreads();  // vmcnt(0) drain -> sA ready, B regs ready

#pragma unroll
    for (int ks = 0; ks < 2; ++ks) {
      const int kx = ks << 5;
      short8 a[4];
#pragma unroll
      for (int i = 0; i < 4; ++i) a[i] = *(const short8*)((const char*)sA + (aoff[i] ^ kx));
#pragma unroll
      for (int i = 0; i < 4; ++i)
#pragma unroll
        for (int j = 0; j < 2; ++j) {
          acc[i][j] = __builtin_amdgcn_mfma_f32_32x32x16_bf16(a[i], bh[j][ks], acc[i][j], 0, 0, 0);
          acc[i][j] = __builtin_amdgcn_mfma_f32_32x32x16_bf16(a[i], bl[j][ks], acc[i][j], 0, 0, 0);
        }
    }
  }

  // epilogue: 32x32 C/D map col=lane&31, row=(reg&3)+8*(reg>>2)+4*(lane>>5)
  float bv[2], cu0[2], cu1[2];
  int nn[2];
#pragma unroll
  for (int j = 0; j < 2; ++j) {
    int n = (bn << 7) + (wc << 6) + (j << 5) + l31;
    nn[j] = n;
    bv[j] = bias[n];
    f32x2 cu = *(const f32x2*)(CU + 2 * n);
    cu0[j] = cu.x; cu1[j] = cu.y;
  }
#pragma unroll
  for (int i = 0; i < 4; ++i) {
    const int mb = (bm << 8) + (wr << 7) + (i << 5) + (g << 2);
#pragma unroll
    for (int q = 0; q < 16; ++q) {
      int m = mb + (q & 3) + ((q >> 2) << 3);
      f32x2 tv = *(const f32x2*)(T + 2 * m);
      float* orow = out + (size_t)m * N_TOT;
#pragma unroll
      for (int j = 0; j < 2; ++j)
        orow[nn[j]] = acc[i][j][q] + bv[j] + tv.x * cu0[j] + tv.y * cu1[j];
    }
  }
}

// ===================== FALLBACK PATH (round-1, proven) ======================
__global__ void wsplit_kernel(const float* __restrict__ Wb, const float* __restrict__ U,
                              const float* __restrict__ S, const float* __restrict__ Vh,
                              const float* __restrict__ P, const float* __restrict__ gv,
                              unsigned short* __restrict__ Whi, unsigned short* __restrict__ Wlo) {
  float c0 = 0.f, c1 = 0.f;
#pragma unroll
  for (int u = 0; u < 16; ++u) { c0 += gv[u] * P[2 * u]; c1 += gv[u] * P[2 * u + 1]; }
  c0 *= S[0]; c1 *= S[1];
  int t = blockIdx.x * 256 + threadIdx.x;
  int o = t >> 9;
  int d = (t & 511) << 2;
  f32x4 wb = *(const f32x4*)(Wb + (size_t)o * K_TOT + d);
  f32x4 v0 = *(const f32x4*)(Vh + d);
  f32x4 v1 = *(const f32x4*)(Vh + K_TOT + d);
  float u0 = U[2 * o] * c0, u1 = U[2 * o + 1] * c1;
  u16x4 hi, lo;
#pragma unroll
  for (int q = 0; q < 4; ++q) {
    float w = wb[q] + u0 * v0[q] + u1 * v1[q];
    unsigned short h = f2bf(w);
    hi[q] = h;
    lo[q] = f2bf(w - bf2f(h));
  }
  *(u16x4*)(Whi + (size_t)o * K_TOT + d) = hi;
  *(u16x4*)(Wlo + (size_t)o * K_TOT + d) = lo;
}

__global__ __launch_bounds__(256) void gemm_split_kernel(
    const float* __restrict__ X, const unsigned short* __restrict__ Whi,
    const unsigned short* __restrict__ Wlo, const float* __restrict__ bias,
    float* __restrict__ out) {
  __shared__ unsigned short sAhi[128 * 32];
  __shared__ unsigned short sAlo[128 * 32];
  __shared__ unsigned short sBhi[128 * 32];
  __shared__ unsigned short sBlo[128 * 32];
  const int tid = threadIdx.x;
  const int lane = tid & 63;
  const int w = tid >> 6;
  const int wr = w >> 1, wc = w & 1;
  const int r = lane & 15, g = lane >> 4;
  const int bn = blockIdx.x, bm = blockIdx.y;
  f32x4 acc[4][4] = {};
  const int arow = tid >> 3;
  const int acol = (tid & 7) << 2;
  const float* Abase = X + (size_t)(bm * 128 + arow) * K_TOT + acol;
  const int brow = lane >> 2;
  const int bcol = (lane & 3) << 3;
  const size_t bgoff = (size_t)(bn * 128 + brow) * K_TOT + bcol;
  for (int kt = 0; kt < K_TOT / 32; ++kt) {
    f32x4 av[4];
#pragma unroll
    for (int p = 0; p < 4; ++p)
      av[p] = *(const f32x4*)(Abase + (size_t)(p * 32) * K_TOT + kt * 32);
    __syncthreads();
#pragma unroll
    for (int ii = 0; ii < 2; ++ii) {
      int chunk = w * 2 + ii;
      size_t go = bgoff + (size_t)(chunk * 16) * K_TOT + kt * 32;
      __builtin_amdgcn_global_load_lds(
          (const __attribute__((address_space(1))) void*)(Whi + go),
          (__attribute__((address_space(3))) void*)(&sBhi[chunk * 512]), 16, 0, 0);
      __builtin_amdgcn_global_load_lds(
          (const __attribute__((address_space(1))) void*)(Wlo + go),
          (__attribute__((address_space(3))) void*)(&sBlo[chunk * 512]), 16, 0, 0);
    }
#pragma unroll
    for (int p = 0; p < 4; ++p) {
      u16x4 hi, lo;
#pragma unroll
      for (int q = 0; q < 4; ++q) {
        float f = av[p][q];
        unsigned short h = f2bf(f);
        hi[q] = h;
        lo[q] = f2bf(f - bf2f(h));
      }
      int off = (arow + p * 32) * 32 + acol;
      *(u16x4*)&sAhi[off] = hi;
      *(u16x4*)&sAlo[off] = lo;
    }
    __syncthreads();
    short8 ah[4], al[4], bh[4], bl[4];
#pragma unroll
    for (int i = 0; i < 4; ++i) {
      int off = (wr * 64 + i * 16 + r) * 32 + g * 8;
      ah[i] = *(const short8*)&sAhi[off];
      al[i] = *(const short8*)&sAlo[off];
    }
#pragma unroll
    for (int j = 0; j < 4; ++j) {
      int off = (wc * 64 + j * 16 + r) * 32 + g * 8;
      bh[j] = *(const short8*)&sBhi[off];
      bl[j] = *(const short8*)&sBlo[off];
    }
#pragma unroll
    for (int i = 0; i < 4; ++i)
#pragma unroll
      for (int j = 0; j < 4; ++j) {
        acc[i][j] = __builtin_amdgcn_mfma_f32_16x16x32_bf16(ah[i], bh[j], acc[i][j], 0, 0, 0);
        acc[i][j] = __builtin_amdgcn_mfma_f32_16x16x32_bf16(ah[i], bl[j], acc[i][j], 0, 0, 0);
        acc[i][j] = __builtin_amdgcn_mfma_f32_16x16x32_bf16(al[i], bh[j], acc[i][j], 0, 0, 0);
      }
  }
#pragma unroll
  for (int j = 0; j < 4; ++j) {
    int n = bn * 128 + wc * 64 + j * 16 + r;
    float bvv = bias[n];
#pragma unroll
    for (int i = 0; i < 4; ++i) {
      int mbase = bm * 128 + wr * 64 + i * 16 + g * 4;
#pragma unroll
      for (int q = 0; q < 4; ++q) {
        out[(size_t)(mbase + q) * N_TOT + n] = acc[i][j][q] + bvv;
      }
    }
  }
}

// ===========================================================================
extern "C" void kernel_launch(void* const* d_in, const int* in_sizes, int n_in,
                              void* d_out, int out_size, void* d_ws, size_t ws_size,
                              hipStream_t stream) {
  const float* x    = (const float*)d_in[0];
  const float* Wb   = (const float*)d_in[1];
  const float* bias = (const float*)d_in[2];
  const float* U    = (const float*)d_in[3];
  const float* S    = (const float*)d_in[4];
  const float* Vh   = (const float*)d_in[5];
  const float* P    = (const float*)d_in[6];
  const float* gv   = (const float*)d_in[7];
  float* out = (float*)d_out;

  const size_t W_ELE = (size_t)N_TOT * K_TOT;   // 4,194,304
  const size_t X_ELE = (size_t)M_TOT * K_TOT;   // 33,554,432
  const size_t TILED_WS = (2 * W_ELE + X_ELE) * 2 + (2 * M_TOT + 2 * N_TOT) * 4;

  if (ws_size >= TILED_WS) {
    unsigned short* Whi_f = (unsigned short*)d_ws;
    unsigned short* Wlo_f = Whi_f + W_ELE;
    unsigned short* Xhi_t = Wlo_f + W_ELE;
    float* T  = (float*)(Xhi_t + X_ELE);
    float* CU = T + 2 * M_TOT;

    wsplit_frag<<<dim3(N_TOT), 256, 0, stream>>>(Wb, U, S, Vh, P, gv, Whi_f, Wlo_f, CU);
    xsplit_tiled<<<dim3(M_TOT / 4), 256, 0, stream>>>(x, Vh, Xhi_t, T);
    gemm4_kernel<<<dim3((M_TOT / 256) * (N_TOT / 128)), 256, 0, stream>>>(
        Xhi_t, Whi_f, Wlo_f, bias, T, CU, out);
  } else {
    unsigned short* Whi = (unsigned short*)d_ws;
    unsigned short* Wlo = Whi + W_ELE;
    wsplit_kernel<<<dim3((N_TOT * K_TOT / 4) / 256), 256, 0, stream>>>(
        Wb, U, S, Vh, P, gv, Whi, Wlo);
    gemm_split_kernel<<<dim3(N_TOT / 128, M_TOT / 128), 256, 0, stream>>>(
        x, Whi, Wlo, bias, out);
  }
}

// Round 6
// 203.869 us; speedup vs baseline: 1.5558x; 1.5558x over previous
//
#include <hip/hip_runtime.h>
#include <hip/hip_bf16.h>

typedef __attribute__((ext_vector_type(8))) short short8;
typedef __attribute__((ext_vector_type(4))) float f32x4;
typedef __attribute__((ext_vector_type(2))) float f32x2;
typedef __attribute__((ext_vector_type(16))) float f32x16;
typedef __attribute__((ext_vector_type(4))) unsigned short u16x4;
typedef __attribute__((ext_vector_type(8))) unsigned short u16x8;

#define M_TOT 16384
#define N_TOT 2048
#define K_TOT 2048

__device__ __forceinline__ unsigned short f2bf(float f) {
  unsigned u = __builtin_bit_cast(unsigned, f);
  u += 0x7FFFu + ((u >> 16) & 1u);   // RNE
  return (unsigned short)(u >> 16);
}
__device__ __forceinline__ float bf2f(unsigned short h) {
  return __builtin_bit_cast(float, (unsigned)h << 16);
}

// ===================== TILED FAST PATH ======================================
// Single-product scheme:
//   out = x_hi @ bf16(W_base)^T + bias + T[m,:]·CU[n,:]
//   T[m,r] = sum_k x[m,k]·Vh[r,k]   (FULL x, exact -> rank-2 delta exact)
//   CU[n,r] = c_r·U[n,r],  c = S*(gv@P)
// Dropped: x_lo@Wb_hi + x_hi@wb_lo  (~1e-2 max, threshold 0.965)
// ws: Whi_t[4M ush] Xhi_t[32M ush] T[32768 f32] CU[4096 f32]
// W tiles: [N/128][K/32] x 8KB, XOR-swizzled;  A tiles: [M/256][K/32] x 16KB.
// swizzle: inner byte = (row*64 + chunk16*16) ^ ((row&7)<<4)

__global__ void wsplit_base(const float* __restrict__ Wb, const float* __restrict__ U,
                            const float* __restrict__ S, const float* __restrict__ Vh,
                            const float* __restrict__ P, const float* __restrict__ gv,
                            unsigned short* __restrict__ Whi_t, float* __restrict__ CU) {
  float c0 = 0.f, c1 = 0.f;
#pragma unroll
  for (int u = 0; u < 16; ++u) { c0 += gv[u] * P[2 * u]; c1 += gv[u] * P[2 * u + 1]; }
  c0 *= S[0]; c1 *= S[1];
  int t = blockIdx.x * 256 + threadIdx.x;
  int o = t >> 8;            // W row (n) 0..2047
  int c = t & 255;           // 16B chunk (8 k-elems)
  int k = c << 3;
  f32x4 wb0 = *(const f32x4*)(Wb + (size_t)o * K_TOT + k);
  f32x4 wb1 = *(const f32x4*)(Wb + (size_t)o * K_TOT + k + 4);
  u16x8 hi;
#pragma unroll
  for (int q = 0; q < 4; ++q) hi[q] = f2bf(wb0[q]);
#pragma unroll
  for (int q = 0; q < 4; ++q) hi[4 + q] = f2bf(wb1[q]);
  int kt = c >> 2, c4 = c & 3;
  size_t base = (size_t)((o >> 7) * 64 + kt) * 8192;               // bytes
  int inner = (((o & 127) << 6) + (c4 << 4)) ^ ((o & 7) << 4);
  *(u16x8*)((char*)Whi_t + base + inner) = hi;
  if (c == 0) {
    CU[2 * o]     = c0 * U[2 * o];
    CU[2 * o + 1] = c1 * U[2 * o + 1];
  }
}

// x -> bf16 hi tiles;  T[m][r] = sum_k x[m,k]*Vh[r,k]  (FULL x)
__global__ void xsplit_tiled(const float* __restrict__ X, const float* __restrict__ Vh,
                             unsigned short* __restrict__ Xhi_t, float* __restrict__ T) {
  int w = threadIdx.x >> 6, lane = threadIdx.x & 63;
  int m = blockIdx.x * 4 + w;
  const float* xr = X + (size_t)m * K_TOT;
  float t0 = 0.f, t1 = 0.f;
#pragma unroll
  for (int p = 0; p < 4; ++p) {
    int c = lane + (p << 6);   // chunk 0..255
    int k = c << 3;
    f32x4 x0 = *(const f32x4*)(xr + k);
    f32x4 x1 = *(const f32x4*)(xr + k + 4);
    f32x4 v0a = *(const f32x4*)(Vh + k);
    f32x4 v0b = *(const f32x4*)(Vh + k + 4);
    f32x4 v1a = *(const f32x4*)(Vh + K_TOT + k);
    f32x4 v1b = *(const f32x4*)(Vh + K_TOT + k + 4);
    u16x8 hi;
#pragma unroll
    for (int q = 0; q < 4; ++q) {
      hi[q] = f2bf(x0[q]);
      t0 += x0[q] * v0a[q]; t1 += x0[q] * v1a[q];
    }
#pragma unroll
    for (int q = 0; q < 4; ++q) {
      hi[4 + q] = f2bf(x1[q]);
      t0 += x1[q] * v0b[q]; t1 += x1[q] * v1b[q];
    }
    int kt = c >> 2;
    size_t base = (size_t)((m >> 8) * 64 + kt) * 16384;            // bytes
    int inner = (((m & 255) << 6) + ((c & 3) << 4)) ^ ((m & 7) << 4);
    *(u16x8*)((char*)Xhi_t + base + inner) = hi;
  }
#pragma unroll
  for (int d = 32; d; d >>= 1) {
    t0 += __shfl_xor(t0, d, 64);
    t1 += __shfl_xor(t1, d, 64);
  }
  if (lane == 0) { T[2 * m] = t0; T[2 * m + 1] = t1; }
}

// Single-product GEMM, 32x32x16 MFMA. BM=256 BN=128 BK=32, 4 waves (2Mx2N),
// wave tile 128x64, acc[4][2]. Cross-tile double-buffered LDS (48KB),
// one barrier per kt; staged loads get the full compute phase as cover.
__global__ __launch_bounds__(256, 2) void gemm5_kernel(
    const unsigned short* __restrict__ Xhi_t, const unsigned short* __restrict__ Whi_t,
    const float* __restrict__ bias, const float* __restrict__ T,
    const float* __restrict__ CU, float* __restrict__ out) {
  __shared__ unsigned short sA[2][8192];   // 2 x 16KB swizzled A
  __shared__ unsigned short sB[2][4096];   // 2 x 8KB swizzled B

  const int tid = threadIdx.x, lane = tid & 63, w = tid >> 6;
  const int wr = w >> 1, wc = w & 1;        // 2M x 2N wave grid
  const int l31 = lane & 31, g = (lane >> 5) & 1;

  // bijective XCD swizzle: 1024 blocks, 1024%8==0
  const int bid = blockIdx.x;
  const int nbk = ((bid & 7) << 7) | (bid >> 3);
  const int bn = nbk & 15, bm = nbk >> 4;

  f32x16 acc[4][2] = {};

  const unsigned short* At = Xhi_t + (size_t)bm * (64 * 8192);
  const unsigned short* Bt = Whi_t + (size_t)bn * (64 * 4096);

  const int sa_i = (w << 11) + (lane << 3);  // A: wave w -> chunks 4w..4w+3 (2048 ush stride)
  const int sb_i = (w << 10) + (lane << 3);  // B: wave w -> chunks 2w..2w+1 (1024 ush stride)
                                             //    ^^^ R5 bug was (w<<9): waves overlapped,
                                             //    ush [2560,4096) of B never staged -> NaN.

#define STAGE5(bufi, kt_) do {                                                            \
    _Pragma("unroll")                                                                     \
    for (int ii = 0; ii < 4; ++ii) {                                                      \
      __builtin_amdgcn_global_load_lds(                                                   \
        (const __attribute__((address_space(1))) void*)(At + (size_t)(kt_) * 8192 + sa_i + ii * 512), \
        (__attribute__((address_space(3))) void*)(&sA[bufi][sa_i + ii * 512]), 16, 0, 0); \
    }                                                                                     \
    _Pragma("unroll")                                                                     \
    for (int ii = 0; ii < 2; ++ii) {                                                      \
      __builtin_amdgcn_global_load_lds(                                                   \
        (const __attribute__((address_space(1))) void*)(Bt + (size_t)(kt_) * 4096 + sb_i + ii * 512), \
        (__attribute__((address_space(3))) void*)(&sB[bufi][sb_i + ii * 512]), 16, 0, 0); \
    }                                                                                     \
  } while (0)

  // fragment swizzled byte offsets (g in bit4; ks toggles bit5 via XOR)
  int aoff[4], boff[2];
#pragma unroll
  for (int i = 0; i < 4; ++i) {
    int row = (wr << 7) + (i << 5) + l31;
    aoff[i] = ((row << 6) + (g << 4)) ^ ((l31 & 7) << 4);
  }
#pragma unroll
  for (int j = 0; j < 2; ++j) {
    int row = (wc << 6) + (j << 5) + l31;
    boff[j] = ((row << 6) + (g << 4)) ^ ((l31 & 7) << 4);
  }

  STAGE5(0, 0);
  __syncthreads();   // vmcnt(0) drain + barrier: tile 0 ready

  for (int kt = 0; kt < 64; ++kt) {
    const int cur = kt & 1;
    if (kt < 63) STAGE5(cur ^ 1, kt + 1);     // prefetch next, no wait
    __builtin_amdgcn_sched_barrier(0);        // keep loads issued before compute

    const char* pA = (const char*)&sA[cur][0];
    const char* pB = (const char*)&sB[cur][0];
#pragma unroll
    for (int ks = 0; ks < 2; ++ks) {
      const int kx = ks << 5;
      short8 a[4], b[2];
#pragma unroll
      for (int i = 0; i < 4; ++i) a[i] = *(const short8*)(pA + (aoff[i] ^ kx));
#pragma unroll
      for (int j = 0; j < 2; ++j) b[j] = *(const short8*)(pB + (boff[j] ^ kx));
#pragma unroll
      for (int i = 0; i < 4; ++i)
#pragma unroll
        for (int j = 0; j < 2; ++j)
          acc[i][j] = __builtin_amdgcn_mfma_f32_32x32x16_bf16(a[i], b[j], acc[i][j], 0, 0, 0);
    }
    __syncthreads();  // drains vmcnt (staged kt+1, covered by compute) + barrier
  }

  // epilogue: 32x32 C/D map col=lane&31, row=(reg&3)+8*(reg>>2)+4*(lane>>5)
  float bv[2], cu0[2], cu1[2];
  int nn[2];
#pragma unroll
  for (int j = 0; j < 2; ++j) {
    int n = (bn << 7) + (wc << 6) + (j << 5) + l31;
    nn[j] = n;
    bv[j] = bias[n];
    f32x2 cu = *(const f32x2*)(CU + 2 * n);
    cu0[j] = cu.x; cu1[j] = cu.y;
  }
#pragma unroll
  for (int i = 0; i < 4; ++i) {
    const int mb = (bm << 8) + (wr << 7) + (i << 5) + (g << 2);
#pragma unroll
    for (int q = 0; q < 16; ++q) {
      int m = mb + (q & 3) + ((q >> 2) << 3);
      f32x2 tv = *(const f32x2*)(T + 2 * m);
      float* orow = out + (size_t)m * N_TOT;
#pragma unroll
      for (int j = 0; j < 2; ++j)
        orow[nn[j]] = acc[i][j][q] + bv[j] + tv.x * cu0[j] + tv.y * cu1[j];
    }
  }
}

// ===================== FALLBACK PATH (round-1, proven) ======================
__global__ void wsplit_kernel(const float* __restrict__ Wb, const float* __restrict__ U,
                              const float* __restrict__ S, const float* __restrict__ Vh,
                              const float* __restrict__ P, const float* __restrict__ gv,
                              unsigned short* __restrict__ Whi, unsigned short* __restrict__ Wlo) {
  float c0 = 0.f, c1 = 0.f;
#pragma unroll
  for (int u = 0; u < 16; ++u) { c0 += gv[u] * P[2 * u]; c1 += gv[u] * P[2 * u + 1]; }
  c0 *= S[0]; c1 *= S[1];
  int t = blockIdx.x * 256 + threadIdx.x;
  int o = t >> 9;
  int d = (t & 511) << 2;
  f32x4 wb = *(const f32x4*)(Wb + (size_t)o * K_TOT + d);
  f32x4 v0 = *(const f32x4*)(Vh + d);
  f32x4 v1 = *(const f32x4*)(Vh + K_TOT + d);
  float u0 = U[2 * o] * c0, u1 = U[2 * o + 1] * c1;
  u16x4 hi, lo;
#pragma unroll
  for (int q = 0; q < 4; ++q) {
    float w = wb[q] + u0 * v0[q] + u1 * v1[q];
    unsigned short h = f2bf(w);
    hi[q] = h;
    lo[q] = f2bf(w - bf2f(h));
  }
  *(u16x4*)(Whi + (size_t)o * K_TOT + d) = hi;
  *(u16x4*)(Wlo + (size_t)o * K_TOT + d) = lo;
}

__global__ __launch_bounds__(256) void gemm_split_kernel(
    const float* __restrict__ X, const unsigned short* __restrict__ Whi,
    const unsigned short* __restrict__ Wlo, const float* __restrict__ bias,
    float* __restrict__ out) {
  __shared__ unsigned short sAhi[128 * 32];
  __shared__ unsigned short sAlo[128 * 32];
  __shared__ unsigned short sBhi[128 * 32];
  __shared__ unsigned short sBlo[128 * 32];
  const int tid = threadIdx.x;
  const int lane = tid & 63;
  const int w = tid >> 6;
  const int wr = w >> 1, wc = w & 1;
  const int r = lane & 15, g = lane >> 4;
  const int bn = blockIdx.x, bm = blockIdx.y;
  f32x4 acc[4][4] = {};
  const int arow = tid >> 3;
  const int acol = (tid & 7) << 2;
  const float* Abase = X + (size_t)(bm * 128 + arow) * K_TOT + acol;
  const int brow = lane >> 2;
  const int bcol = (lane & 3) << 3;
  const size_t bgoff = (size_t)(bn * 128 + brow) * K_TOT + bcol;
  for (int kt = 0; kt < K_TOT / 32; ++kt) {
    f32x4 av[4];
#pragma unroll
    for (int p = 0; p < 4; ++p)
      av[p] = *(const f32x4*)(Abase + (size_t)(p * 32) * K_TOT + kt * 32);
    __syncthreads();
#pragma unroll
    for (int ii = 0; ii < 2; ++ii) {
      int chunk = w * 2 + ii;
      size_t go = bgoff + (size_t)(chunk * 16) * K_TOT + kt * 32;
      __builtin_amdgcn_global_load_lds(
          (const __attribute__((address_space(1))) void*)(Whi + go),
          (__attribute__((address_space(3))) void*)(&sBhi[chunk * 512]), 16, 0, 0);
      __builtin_amdgcn_global_load_lds(
          (const __attribute__((address_space(1))) void*)(Wlo + go),
          (__attribute__((address_space(3))) void*)(&sBlo[chunk * 512]), 16, 0, 0);
    }
#pragma unroll
    for (int p = 0; p < 4; ++p) {
      u16x4 hi, lo;
#pragma unroll
      for (int q = 0; q < 4; ++q) {
        float f = av[p][q];
        unsigned short h = f2bf(f);
        hi[q] = h;
        lo[q] = f2bf(f - bf2f(h));
      }
      int off = (arow + p * 32) * 32 + acol;
      *(u16x4*)&sAhi[off] = hi;
      *(u16x4*)&sAlo[off] = lo;
    }
    __syncthreads();
    short8 ah[4], al[4], bh[4], bl[4];
#pragma unroll
    for (int i = 0; i < 4; ++i) {
      int off = (wr * 64 + i * 16 + r) * 32 + g * 8;
      ah[i] = *(const short8*)&sAhi[off];
      al[i] = *(const short8*)&sAlo[off];
    }
#pragma unroll
    for (int j = 0; j < 4; ++j) {
      int off = (wc * 64 + j * 16 + r) * 32 + g * 8;
      bh[j] = *(const short8*)&sBhi[off];
      bl[j] = *(const short8*)&sBlo[off];
    }
#pragma unroll
    for (int i = 0; i < 4; ++i)
#pragma unroll
      for (int j = 0; j < 4; ++j) {
        acc[i][j] = __builtin_amdgcn_mfma_f32_16x16x32_bf16(ah[i], bh[j], acc[i][j], 0, 0, 0);
        acc[i][j] = __builtin_amdgcn_mfma_f32_16x16x32_bf16(ah[i], bl[j], acc[i][j], 0, 0, 0);
        acc[i][j] = __builtin_amdgcn_mfma_f32_16x16x32_bf16(al[i], bh[j], acc[i][j], 0, 0, 0);
      }
  }
#pragma unroll
  for (int j = 0; j < 4; ++j) {
    int n = bn * 128 + wc * 64 + j * 16 + r;
    float bvv = bias[n];
#pragma unroll
    for (int i = 0; i < 4; ++i) {
      int mbase = bm * 128 + wr * 64 + i * 16 + g * 4;
#pragma unroll
      for (int q = 0; q < 4; ++q) {
        out[(size_t)(mbase + q) * N_TOT + n] = acc[i][j][q] + bvv;
      }
    }
  }
}

// ===========================================================================
extern "C" void kernel_launch(void* const* d_in, const int* in_sizes, int n_in,
                              void* d_out, int out_size, void* d_ws, size_t ws_size,
                              hipStream_t stream) {
  const float* x    = (const float*)d_in[0];
  const float* Wb   = (const float*)d_in[1];
  const float* bias = (const float*)d_in[2];
  const float* U    = (const float*)d_in[3];
  const float* S    = (const float*)d_in[4];
  const float* Vh   = (const float*)d_in[5];
  const float* P    = (const float*)d_in[6];
  const float* gv   = (const float*)d_in[7];
  float* out = (float*)d_out;

  const size_t W_ELE = (size_t)N_TOT * K_TOT;   // 4,194,304
  const size_t X_ELE = (size_t)M_TOT * K_TOT;   // 33,554,432
  const size_t TILED_WS = (W_ELE + X_ELE) * 2 + (2 * M_TOT + 2 * N_TOT) * 4;

  if (ws_size >= TILED_WS) {
    unsigned short* Whi_t = (unsigned short*)d_ws;
    unsigned short* Xhi_t = Whi_t + W_ELE;
    float* T  = (float*)(Xhi_t + X_ELE);
    float* CU = T + 2 * M_TOT;

    wsplit_base<<<dim3(N_TOT), 256, 0, stream>>>(Wb, U, S, Vh, P, gv, Whi_t, CU);
    xsplit_tiled<<<dim3(M_TOT / 4), 256, 0, stream>>>(x, Vh, Xhi_t, T);
    gemm5_kernel<<<dim3((M_TOT / 256) * (N_TOT / 128)), 256, 0, stream>>>(
        Xhi_t, Whi_t, bias, T, CU, out);
  } else {
    unsigned short* Whi = (unsigned short*)d_ws;
    unsigned short* Wlo = Whi + W_ELE;
    wsplit_kernel<<<dim3((N_TOT * K_TOT / 4) / 256), 256, 0, stream>>>(
        Wb, U, S, Vh, P, gv, Whi, Wlo);
    gemm_split_kernel<<<dim3(N_TOT / 128, M_TOT / 128), 256, 0, stream>>>(
        x, Whi, Wlo, bias, out);
  }
}